// Round 6
// baseline (726.987 us; speedup 1.0000x reference)
//
#include <hip/hip_runtime.h>
#include <cstdint>
#include <cstddef>

// ---------------------------------------------------------------------------
// BsPINN forward, fully-fused persistent kernel (round 17).
// R16 post-mortem: swizzle works (conflicts 0) but the 3-GEMM chain is flat
// (~503us, +-3% noise). The chain moves ~1.3 GB HBM of activations that fit
// in LDS: 64 rows x 1024 cols f16 = 128 KB. So fuse the ENTIRE network:
//   grid 1024 blocks x 512 threads; block owns 64 rows end-to-end.
//   h0 (layer0 math) -> LDS; L1/L2/L3 = MFMA sweeps with A from LDS-h,
//   B streamed from f16 Wt planes in global (L2-resident: 2+1+0.5 MB).
//   ZERO barriers inside K-loops (no LDS staging of W) — removes the
//   barrier-drain failure mode of R12-R15 structurally.
//   Layer transition: bias+tanh -> f16 -> swizzled LDS write (1 barrier each
//   side). Block-diag layers = per-wave restricted k-range.
//   Final: tanh . Wl dot in regs -> shfl + LDS reduce -> direct out write.
// Eliminated: P planes (131 MB HBM traffic/layer), init_out, atomics,
// layer0 kernel, 6 GEMM dispatches. Workspace: 6 MiB (3 f16 Wt planes).
// LDS h swizzle: col ^ ((row&7)<<3) (G4 formula for stride-2KB rows):
// A-frag reads land uniform 8 lanes/16B-group = bandwidth-minimal.
// Register budget: acc[4][8]=128 + bfA/bfB=64 + af=16 + addr ~= 238 < 256
// (512-thread block, NO min-wave launch bound — R13 spill lesson).
// Numerics identical to validated path (f16 W/h, fp32 acc, same tanh):
// absmax expected unchanged (2.44e-4).
// ---------------------------------------------------------------------------

typedef _Float16  f16x8   __attribute__((ext_vector_type(8)));
typedef float     floatx4 __attribute__((ext_vector_type(4)));
typedef float     floatx8 __attribute__((ext_vector_type(8)));

__device__ __forceinline__ float tanh_fast(float x) {
    float e = __expf(2.0f * x);
    return 1.0f - 2.0f / (e + 1.0f);
}

// ---------------------------------------------------------------------------
// Weight transpose + f16 convert: fp32 W[K=1024][N=1024] -> f16 Wt[N][K].
// ---------------------------------------------------------------------------
__global__ __launch_bounds__(256)
void transposeH(const float* __restrict__ W, _Float16* __restrict__ Wt) {
    __shared__ float tile[32][33];
    const int tx = threadIdx.x & 31;
    const int ty = threadIdx.x >> 5;     // 0..7
    #pragma unroll
    for (int j = 0; j < 4; ++j) {
        int r = ty + j * 8;
        tile[r][tx] = W[(size_t)(blockIdx.y * 32 + r) * 1024 + blockIdx.x * 32 + tx];
    }
    __syncthreads();
    #pragma unroll
    for (int j = 0; j < 4; ++j) {
        int r = ty + j * 8;
        Wt[(size_t)(blockIdx.x * 32 + r) * 1024 + blockIdx.y * 32 + tx] =
            (_Float16)tile[tx][r];
    }
}

// ---------------------------------------------------------------------------
// One layer's GEMM sweep: acc[i][j] += h[64 x k-range] @ Wt[cols, k-range].
// A-frags from LDS h (XOR-swizzled), B-frags streamed from global Wt with
// a 2-deep register double-buffer (bfA/bfB). No barriers, no LDS writes.
// Wave computes all 4 m-tiles (64 rows) x its 8 n-tiles (128 cols).
// ---------------------------------------------------------------------------
template <int KSTEPS>
__device__ __forceinline__ void gemm_layer(const _Float16* __restrict__ Wt,
                                           const _Float16* h, int kbeg,
                                           int wn, int r, int q,
                                           floatx4 (&acc)[4][8]) {
    const int swzm = (r & 7) << 3;
    const _Float16* wb = Wt + (size_t)(wn + r) * 1024 + kbeg + q * 8;
    const _Float16* hb = h + r * 1024;       // + i*16384 per m-tile

    f16x8 bfA[8], bfB[8];
    #pragma unroll
    for (int j = 0; j < 8; ++j)
        bfA[j] = *(const f16x8*)(wb + j * 16384);

    #pragma unroll
    for (int tt = 0; tt < KSTEPS / 2; ++tt) {
        const int k0 = kbeg + tt * 64;       // even step k; odd step k0+32
        // prefetch odd step's B
        #pragma unroll
        for (int j = 0; j < 8; ++j)
            bfB[j] = *(const f16x8*)(wb + j * 16384 + tt * 64 + 32);

        f16x8 af[4];
        #pragma unroll
        for (int i = 0; i < 4; ++i)
            af[i] = *(const f16x8*)(hb + i * 16384 + ((k0 + q * 8) ^ swzm));
        #pragma unroll
        for (int i = 0; i < 4; ++i)
            #pragma unroll
            for (int j = 0; j < 8; ++j)
                acc[i][j] = __builtin_amdgcn_mfma_f32_16x16x32_f16(af[i], bfA[j], acc[i][j], 0, 0, 0);

        if (tt + 1 < KSTEPS / 2) {           // prefetch next even step's B
            #pragma unroll
            for (int j = 0; j < 8; ++j)
                bfA[j] = *(const f16x8*)(wb + j * 16384 + tt * 64 + 64);
        }

        #pragma unroll
        for (int i = 0; i < 4; ++i)
            af[i] = *(const f16x8*)(hb + i * 16384 + ((k0 + 32 + q * 8) ^ swzm));
        #pragma unroll
        for (int i = 0; i < 4; ++i)
            #pragma unroll
            for (int j = 0; j < 8; ++j)
                acc[i][j] = __builtin_amdgcn_mfma_f32_16x16x32_f16(af[i], bfB[j], acc[i][j], 0, 0, 0);
    }
}

// bias + tanh + f16 + swizzled LDS write (C-layout: row=i*16+q*4+rr, col=wn+j*16+r)
__device__ __forceinline__ void store_h(_Float16* h, const float* __restrict__ bias,
                                        const floatx4 (&acc)[4][8],
                                        int wn, int r, int q) {
    #pragma unroll
    for (int j = 0; j < 8; ++j) {
        const int col = wn + j * 16 + r;
        const float bv = bias[col];
        #pragma unroll
        for (int i = 0; i < 4; ++i) {
            #pragma unroll
            for (int rr = 0; rr < 4; ++rr) {
                const int row = i * 16 + q * 4 + rr;
                h[row * 1024 + (col ^ ((row & 7) << 3))] =
                    (_Float16)tanh_fast(acc[i][j][rr] + bv);
            }
        }
    }
}

// ---------------------------------------------------------------------------
// The fused network. Block = 64 rows. 512 threads = 8 waves; wave w owns
// cols [w*128, w*128+128) at every layer (8 n-tiles), all 64 rows (4 m-tiles).
// ---------------------------------------------------------------------------
__global__ __launch_bounds__(512)
void fused_forward(const float* __restrict__ X, const float* __restrict__ W0,
                   const float* __restrict__ b0,
                   const _Float16* __restrict__ Wt1, const float* __restrict__ b1,
                   const _Float16* __restrict__ Wt2, const float* __restrict__ b2,
                   const _Float16* __restrict__ Wt3, const float* __restrict__ b3,
                   const float* __restrict__ Wl, const float* __restrict__ bl,
                   float* __restrict__ out) {
    __shared__ _Float16 h[64 * 1024];        // 128 KB, XOR-swizzled rows

    const int tid  = threadIdx.x;
    const int lane = tid & 63;
    const int w    = tid >> 6;               // 0..7
    const int r    = lane & 15, q = lane >> 4;
    const int wn   = w << 7;                 // wave col base
    const int row0 = blockIdx.x << 6;        // global row base

    // ---- h0 = tanh(norm(X) @ W0 + b0): thread fills 1 row x 128 cols.
    {
        const int frow  = tid >> 3;          // 0..63
        const int fcol0 = (tid & 7) << 7;    // 0,128,...,896
        const float x0 = X[(row0 + frow) * 2 + 0];
        const float x1 = X[(row0 + frow) * 2 + 1];
        const float xa = x0 * 0.31830988618379067f - 1.0f;   // x0/pi - 1
        const float xb = 2.0f * x1 - 1.0f;
        const int fswz = (frow & 7) << 3;
        #pragma unroll
        for (int c = 0; c < 128; c += 8) {
            const int col = fcol0 + c;
            floatx8 wa = *(const floatx8*)(W0 + col);
            floatx8 wv = *(const floatx8*)(W0 + 1024 + col);
            floatx8 bb = *(const floatx8*)(b0 + col);
            f16x8 o;
            #pragma unroll
            for (int jj = 0; jj < 8; ++jj)
                o[jj] = (_Float16)tanh_fast(fmaf(xa, wa[jj], fmaf(xb, wv[jj], bb[jj])));
            *(f16x8*)(h + frow * 1024 + (col ^ fswz)) = o;
        }
    }
    __syncthreads();

    floatx4 acc[4][8];

    // ---- L1: dense, K=1024
    #pragma unroll
    for (int i = 0; i < 4; ++i)
        #pragma unroll
        for (int j = 0; j < 8; ++j) acc[i][j] = floatx4{0.f, 0.f, 0.f, 0.f};
    gemm_layer<32>(Wt1, h, 0, wn, r, q, acc);
    __syncthreads();                          // all h0 reads done
    store_h(h, b1, acc, wn, r, q);
    __syncthreads();                          // h1 visible

    // ---- L2: block-diag 2 x 512
    #pragma unroll
    for (int i = 0; i < 4; ++i)
        #pragma unroll
        for (int j = 0; j < 8; ++j) acc[i][j] = floatx4{0.f, 0.f, 0.f, 0.f};
    gemm_layer<16>(Wt2, h, (wn >> 9) << 9, wn, r, q, acc);
    __syncthreads();
    store_h(h, b2, acc, wn, r, q);
    __syncthreads();                          // h2 visible

    // ---- L3: block-diag 4 x 256, fused with final dot
    #pragma unroll
    for (int i = 0; i < 4; ++i)
        #pragma unroll
        for (int j = 0; j < 8; ++j) acc[i][j] = floatx4{0.f, 0.f, 0.f, 0.f};
    gemm_layer<8>(Wt3, h, (wn >> 8) << 8, wn, r, q, acc);

    float bv[8], wl[8];
    #pragma unroll
    for (int j = 0; j < 8; ++j) {
        const int col = wn + j * 16 + r;
        bv[j] = b3[col];
        wl[j] = Wl[col];
    }
    __syncthreads();                          // all h2 reads done; h reusable
    float* red = (float*)h;                   // 8 waves x 64 rows partials
    #pragma unroll
    for (int i = 0; i < 4; ++i) {
        #pragma unroll
        for (int rr = 0; rr < 4; ++rr) {
            float p = 0.f;
            #pragma unroll
            for (int j = 0; j < 8; ++j)
                p = fmaf(tanh_fast(acc[i][j][rr] + bv[j]), wl[j], p);
            p += __shfl_down(p, 8);
            p += __shfl_down(p, 4);
            p += __shfl_down(p, 2);
            p += __shfl_down(p, 1);
            if (r == 0) red[w * 64 + i * 16 + q * 4 + rr] = p;
        }
    }
    __syncthreads();
    if (tid < 64) {
        float s = bl[0];
        #pragma unroll
        for (int ww = 0; ww < 8; ++ww) s += red[ww * 64 + tid];
        out[row0 + tid] = s;
    }
}

// ---------------------------------------------------------------------------
extern "C" void kernel_launch(void* const* d_in, const int* in_sizes, int n_in,
                              void* d_out, int out_size, void* d_ws, size_t ws_size,
                              hipStream_t stream) {
    const float* X  = (const float*)d_in[0];
    const float* W0 = (const float*)d_in[1];
    const float* b0 = (const float*)d_in[2];
    const float* W1 = (const float*)d_in[3];
    const float* b1 = (const float*)d_in[4];
    const float* W2 = (const float*)d_in[5];
    const float* b2 = (const float*)d_in[6];
    const float* W3 = (const float*)d_in[7];
    const float* b3 = (const float*)d_in[8];
    const float* Wl = (const float*)d_in[9];
    const float* bl = (const float*)d_in[10];
    float* out = (float*)d_out;

    const int Nrows = in_sizes[0] / 2;                 // 65536
    const size_t WT = 1024 * 1024;                     // elems per f16 plane

    if (ws_size < 3 * WT * 2) return;                  // needs 6 MiB
    _Float16* Wt1 = (_Float16*)d_ws;
    _Float16* Wt2 = Wt1 + WT;
    _Float16* Wt3 = Wt2 + WT;

    const dim3 tb(256);
    transposeH<<<dim3(32, 32), tb, 0, stream>>>(W1, Wt1);
    transposeH<<<dim3(32, 32), tb, 0, stream>>>(W2, Wt2);
    transposeH<<<dim3(32, 32), tb, 0, stream>>>(W3, Wt3);

    fused_forward<<<dim3(Nrows / 64), dim3(512), 0, stream>>>(
        X, W0, b0, Wt1, b1, Wt2, b2, Wt3, b3, Wl, bl, out);
}

// Round 8
// 661.364 us; speedup vs baseline: 1.0992x; 1.0992x over previous
//
#include <hip/hip_runtime.h>
#include <cstdint>
#include <cstddef>

// ---------------------------------------------------------------------------
// BsPINN forward, fully-fused persistent kernel (round 19 = R18 resubmit;
// R18 bench was an infra failure — container died twice, no counters).
// R17 post-mortem (710us): (1) compiler chose 128-VGPR budget w/o min-wave
// hint -> ~30 regs/thread spilled (WRITE_SIZE 126MB, VGPR_Count 128);
// (2) store_h scalar writes 4-way bank-conflicted + h0-fill lanes collapsed
// to 2 bank groups (14.7M conflicts); (3) MfmaUtil 14% = starved pipe.
// Structure is right (MFMA floor 96us + L2 weight-stream floor 104us).
// R18/R19 fixes:
//   - __launch_bounds__(512, 1): allocator told 1 wave/EU is OK -> no
//     heuristic reg cap, no spill. Live-reg budget trimmed to ~205:
//     acc[4][8]=128, B-ring bf[3][4]=48 (half-k-step prefetch, distance
//     = 32 MFMAs ~130cyc, covers L2 latency w/ 2 waves/SIMD co-issue),
//     af[4]=16. All array indexing static under full unroll.
//   - swizzle redesigned: phys_col = col ^ (((row>>2)&3)<<4).
//     store_h (rows vary only in q): 4 q-groups split on bank bits 3-4,
//     16 r-lanes -> 8 banks x 2-way (free). af reads: (q0,q1^r2,r3)
//     uniform -> 8 lanes per 4-bank group = b128 minimum (conflict-free).
//     h0-fill col-slots (tid&7)*8 + 64k -> bank bits 3-5 vary per lane.
// Layout: 1024 blocks x 512 thr; block owns 64 rows; h[64][1024] f16 in
// 128KB LDS; wave w owns cols [w*128,+128) every layer; B streamed from
// f16 Wt planes (L2-resident, ~3.5MB/XCD); zero barriers in K-loops;
// 6 barriers total per block. Final dot fused; out written directly.
// ---------------------------------------------------------------------------

typedef _Float16  f16x8   __attribute__((ext_vector_type(8)));
typedef float     floatx4 __attribute__((ext_vector_type(4)));
typedef float     floatx8 __attribute__((ext_vector_type(8)));

__device__ __forceinline__ float tanh_fast(float x) {
    float e = __expf(2.0f * x);
    return 1.0f - 2.0f / (e + 1.0f);
}

// ---------------------------------------------------------------------------
// Weight transpose + f16 convert: fp32 W[K=1024][N=1024] -> f16 Wt[N][K].
// ---------------------------------------------------------------------------
__global__ __launch_bounds__(256)
void transposeH(const float* __restrict__ W, _Float16* __restrict__ Wt) {
    __shared__ float tile[32][33];
    const int tx = threadIdx.x & 31;
    const int ty = threadIdx.x >> 5;     // 0..7
    #pragma unroll
    for (int j = 0; j < 4; ++j) {
        int r = ty + j * 8;
        tile[r][tx] = W[(size_t)(blockIdx.y * 32 + r) * 1024 + blockIdx.x * 32 + tx];
    }
    __syncthreads();
    #pragma unroll
    for (int j = 0; j < 4; ++j) {
        int r = ty + j * 8;
        Wt[(size_t)(blockIdx.x * 32 + r) * 1024 + blockIdx.y * 32 + tx] =
            (_Float16)tile[tx][r];
    }
}

// ---------------------------------------------------------------------------
// One layer: acc[i][j] += h[64 x Krange] @ Wt[cols, Krange].
// A-frags from LDS h (swizzled), B streamed from global Wt via a 3-slot
// half-k-step prefetch ring (distance = 32 MFMA). No barriers, no LDS writes.
// ---------------------------------------------------------------------------
template <int KSTEPS>
__device__ __forceinline__ void gemm_layer(const _Float16* __restrict__ Wt,
                                           const _Float16* h, int kbeg,
                                           int wn, int r, int q, int swzm,
                                           floatx4 (&acc)[4][8]) {
    const _Float16* wb = Wt + (size_t)(wn + r) * 1024 + kbeg + q * 8;
    const _Float16* hb = h + r * 1024;          // row = i*16 + r

    f16x8 bf[3][4];
    #pragma unroll
    for (int j = 0; j < 4; ++j) bf[0][j] = *(const f16x8*)(wb + j * 16384);
    #pragma unroll
    for (int j = 0; j < 4; ++j) bf[1][j] = *(const f16x8*)(wb + (4 + j) * 16384);

    #pragma unroll
    for (int t = 0; t < KSTEPS; ++t) {
        const int k0 = kbeg + t * 32;
        f16x8 af[4];
        #pragma unroll
        for (int i = 0; i < 4; ++i)
            af[i] = *(const f16x8*)(hb + i * 16384 + ((k0 + q * 8) ^ swzm));

        if (t + 1 < KSTEPS) {                   // prefetch (t+1, j0..3)
            #pragma unroll
            for (int j = 0; j < 4; ++j)
                bf[(2 * t + 2) % 3][j] = *(const f16x8*)(wb + j * 16384 + (t + 1) * 32);
        }
        #pragma unroll
        for (int i = 0; i < 4; ++i)
            #pragma unroll
            for (int j = 0; j < 4; ++j)
                acc[i][j] = __builtin_amdgcn_mfma_f32_16x16x32_f16(
                    af[i], bf[(2 * t) % 3][j], acc[i][j], 0, 0, 0);

        if (t + 1 < KSTEPS) {                   // prefetch (t+1, j4..7)
            #pragma unroll
            for (int j = 0; j < 4; ++j)
                bf[(2 * t + 3) % 3][j] = *(const f16x8*)(wb + (4 + j) * 16384 + (t + 1) * 32);
        }
        #pragma unroll
        for (int i = 0; i < 4; ++i)
            #pragma unroll
            for (int j = 0; j < 4; ++j)
                acc[i][4 + j] = __builtin_amdgcn_mfma_f32_16x16x32_f16(
                    af[i], bf[(2 * t + 1) % 3][j], acc[i][4 + j], 0, 0, 0);
    }
}

// bias + tanh + f16 + swizzled LDS write. Fragment: col=lane&15 within 16,
// row = i*16 + q*4 + rr  =>  ((row>>2)&3) == q  => swz = q<<4 per lane.
__device__ __forceinline__ void store_h(_Float16* h, const float* __restrict__ bias,
                                        const floatx4 (&acc)[4][8],
                                        int wn, int r, int q) {
    const int cswz = q << 4;
    #pragma unroll
    for (int j = 0; j < 8; ++j) {
        const int col = wn + j * 16 + r;
        const float bv = bias[col];
        #pragma unroll
        for (int i = 0; i < 4; ++i) {
            #pragma unroll
            for (int rr = 0; rr < 4; ++rr) {
                const int row = i * 16 + q * 4 + rr;
                h[row * 1024 + (col ^ cswz)] = (_Float16)tanh_fast(acc[i][j][rr] + bv);
            }
        }
    }
}

// ---------------------------------------------------------------------------
// Fused network. Block = 64 rows; 512 threads = 8 waves; wave w owns cols
// [w*128, +128) (8 n-tiles) at every layer, all 4 m-tiles (64 rows).
// ---------------------------------------------------------------------------
__global__ __launch_bounds__(512, 1)
void fused_forward(const float* __restrict__ X, const float* __restrict__ W0,
                   const float* __restrict__ b0,
                   const _Float16* __restrict__ Wt1, const float* __restrict__ b1,
                   const _Float16* __restrict__ Wt2, const float* __restrict__ b2,
                   const _Float16* __restrict__ Wt3, const float* __restrict__ b3,
                   const float* __restrict__ Wl, const float* __restrict__ bl,
                   float* __restrict__ out) {
    __shared__ _Float16 h[64 * 1024];        // 128 KB, col ^ ((row>>2)&3)<<4

    const int tid  = threadIdx.x;
    const int lane = tid & 63;
    const int w    = tid >> 6;               // 0..7
    const int r    = lane & 15, q = lane >> 4;
    const int wn   = w << 7;                 // wave col base
    const int row0 = blockIdx.x << 6;        // global row base
    const int swzm = ((r >> 2) & 3) << 4;    // af-read swizzle (row = i*16+r)

    // ---- h0 = tanh(norm(X) @ W0 + b0): row tid>>3, col slots (tid&7)*8+64k.
    {
        const int frow = tid >> 3;           // 0..63
        const int cs   = (tid & 7) << 3;     // 0..56
        const float x0 = X[(row0 + frow) * 2 + 0];
        const float x1 = X[(row0 + frow) * 2 + 1];
        const float xa = x0 * 0.31830988618379067f - 1.0f;   // x0/pi - 1
        const float xb = 2.0f * x1 - 1.0f;
        const int fswz = ((frow >> 2) & 3) << 4;
        #pragma unroll
        for (int k = 0; k < 16; ++k) {
            const int col = cs + k * 64;
            floatx8 wa = *(const floatx8*)(W0 + col);
            floatx8 wv = *(const floatx8*)(W0 + 1024 + col);
            floatx8 bb = *(const floatx8*)(b0 + col);
            f16x8 o;
            #pragma unroll
            for (int jj = 0; jj < 8; ++jj)
                o[jj] = (_Float16)tanh_fast(fmaf(xa, wa[jj], fmaf(xb, wv[jj], bb[jj])));
            *(f16x8*)(h + frow * 1024 + (col ^ fswz)) = o;
        }
    }
    __syncthreads();

    floatx4 acc[4][8];

    // ---- L1: dense, K=1024
    #pragma unroll
    for (int i = 0; i < 4; ++i)
        #pragma unroll
        for (int j = 0; j < 8; ++j) acc[i][j] = floatx4{0.f, 0.f, 0.f, 0.f};
    gemm_layer<32>(Wt1, h, 0, wn, r, q, swzm, acc);
    __syncthreads();                          // all h0 reads done
    store_h(h, b1, acc, wn, r, q);
    __syncthreads();                          // h1 visible

    // ---- L2: block-diag 2 x 512
    #pragma unroll
    for (int i = 0; i < 4; ++i)
        #pragma unroll
        for (int j = 0; j < 8; ++j) acc[i][j] = floatx4{0.f, 0.f, 0.f, 0.f};
    gemm_layer<16>(Wt2, h, (wn >> 9) << 9, wn, r, q, swzm, acc);
    __syncthreads();
    store_h(h, b2, acc, wn, r, q);
    __syncthreads();                          // h2 visible

    // ---- L3: block-diag 4 x 256, fused with final dot
    #pragma unroll
    for (int i = 0; i < 4; ++i)
        #pragma unroll
        for (int j = 0; j < 8; ++j) acc[i][j] = floatx4{0.f, 0.f, 0.f, 0.f};
    gemm_layer<8>(Wt3, h, (wn >> 8) << 8, wn, r, q, swzm, acc);

    float bv[8], wl[8];
    #pragma unroll
    for (int j = 0; j < 8; ++j) {
        const int col = wn + j * 16 + r;
        bv[j] = b3[col];
        wl[j] = Wl[col];
    }
    __syncthreads();                          // all h2 reads done; h reusable
    float* red = (float*)h;                   // 8 waves x 64 row-partials
    #pragma unroll
    for (int i = 0; i < 4; ++i) {
        #pragma unroll
        for (int rr = 0; rr < 4; ++rr) {
            float p = 0.f;
            #pragma unroll
            for (int j = 0; j < 8; ++j)
                p = fmaf(tanh_fast(acc[i][j][rr] + bv[j]), wl[j], p);
            p += __shfl_down(p, 8);
            p += __shfl_down(p, 4);
            p += __shfl_down(p, 2);
            p += __shfl_down(p, 1);
            if (r == 0) red[w * 64 + i * 16 + q * 4 + rr] = p;
        }
    }
    __syncthreads();
    if (tid < 64) {
        float s = bl[0];
        #pragma unroll
        for (int ww = 0; ww < 8; ++ww) s += red[ww * 64 + tid];
        out[row0 + tid] = s;
    }
}

// ---------------------------------------------------------------------------
extern "C" void kernel_launch(void* const* d_in, const int* in_sizes, int n_in,
                              void* d_out, int out_size, void* d_ws, size_t ws_size,
                              hipStream_t stream) {
    const float* X  = (const float*)d_in[0];
    const float* W0 = (const float*)d_in[1];
    const float* b0 = (const float*)d_in[2];
    const float* W1 = (const float*)d_in[3];
    const float* b1 = (const float*)d_in[4];
    const float* W2 = (const float*)d_in[5];
    const float* b2 = (const float*)d_in[6];
    const float* W3 = (const float*)d_in[7];
    const float* b3 = (const float*)d_in[8];
    const float* Wl = (const float*)d_in[9];
    const float* bl = (const float*)d_in[10];
    float* out = (float*)d_out;

    const int Nrows = in_sizes[0] / 2;                 // 65536
    const size_t WT = 1024 * 1024;                     // elems per f16 plane

    if (ws_size < 3 * WT * 2) return;                  // needs 6 MiB
    _Float16* Wt1 = (_Float16*)d_ws;
    _Float16* Wt2 = Wt1 + WT;
    _Float16* Wt3 = Wt2 + WT;

    const dim3 tb(256);
    transposeH<<<dim3(32, 32), tb, 0, stream>>>(W1, Wt1);
    transposeH<<<dim3(32, 32), tb, 0, stream>>>(W2, Wt2);
    transposeH<<<dim3(32, 32), tb, 0, stream>>>(W3, Wt3);

    fused_forward<<<dim3(Nrows / 64), dim3(512), 0, stream>>>(
        X, W0, b0, Wt1, b1, Wt2, b2, Wt3, b3, Wl, bl, out);
}